// Round 1
// baseline (6201.009 us; speedup 1.0000x reference)
//
#include <hip/hip_runtime.h>
#include <hip/hip_bf16.h>
#include <stdint.h>

#define SUBU 20
#define E_NO 2000
#define I_NO 500
#define T_DATA 20000
#define T_SYNK 200
#define T_HISTK 50
#define SBAS 3
#define HBAS 3
#define TPAD 20096          // 1256 * 16
#define KMAX 12             // max nnz per C_den row we support (20 @ 10% density)

// workspace float offsets
#define OFF_SYN  0          // [TPAD][20]
#define OFF_INE  401920     // [20][TPAD]
#define OFF_INI  803840     // [20][TPAD]
#define OFF_KE   1205760    // [20][200]
#define OFF_KI   1209760    // [20][200]
#define OFF_HK   1213760    // [20][50]
#define OFF_MW   1214760    // [20][KMAX]
#define OFF_MIDX 1215000    // [20][KMAX] ints
#define OFF_PAR  1215240    // Theta[20], Wsub0, Vo
#define OFF_FLAG 1215264    // int bf16 flag

__device__ __forceinline__ float bf2f(unsigned short u){
  unsigned v = ((unsigned)u) << 16; float f; __builtin_memcpy(&f, &v, 4); return f;
}
__device__ __forceinline__ float ldany(const void* p, int i, int bf){
  return bf ? bf2f(((const unsigned short*)p)[i]) : ((const float*)p)[i];
}

// ---------------- dtype detection: S_e is exactly {0,1} -------------------
__global__ __launch_bounds__(256) void k_detect(const void* s_e, int* flag){
  __shared__ int found;
  if (threadIdx.x == 0) found = 0;
  __syncthreads();
  const unsigned* w = (const unsigned*)s_e;
  int hit = 0;
  for (int i = threadIdx.x; i < 65536; i += 256){
    unsigned x = w[i];
    if (x == 0x00003F80u || x == 0x3F803F80u) hit = 1;   // low-half bf16 1.0 => bf16 buffer
  }
  if (hit) atomicOr(&found, 1);
  __syncthreads();
  if (threadIdx.x == 0) *flag = found;
}

// ---------------- precompute alpha kernels, sparse M, params --------------
__global__ __launch_bounds__(256) void k_prep(
    const void* Cden, const void* Wsyn, const void* Tausyn, const void* Dsyn,
    const void* Whist, const void* Tauhist, const void* Dhist,
    const void* Wsub, const void* Vo, const void* Theta, float* ws){
  int* wsi = (int*)ws;
  const int bf = wsi[OFF_FLAG];
  // synaptic kernels ke/ki [20][200]
  for (int idx = threadIdx.x; idx < SUBU * T_SYNK; idx += 256){
    int s = idx / T_SYNK, t = idx % T_SYNK;
    for (int c = 0; c < 2; ++c){
      float delta = __expf(ldany(Dsyn, s*2 + c, bf));
      float acc = 0.f;
      for (int b = 0; b < SBAS; ++b){
        float tau = __expf(ldany(Tausyn, b*2 + c, bf));
        float w   = ldany(Wsyn, (s*SBAS + b)*2 + c, bf);
        float tt  = fmaxf((float)t - delta, 0.f) / tau;
        acc += w * tt * __expf(-tt);
      }
      ws[(c == 0 ? OFF_KE : OFF_KI) + s*T_SYNK + t] = acc;
    }
  }
  // history kernel hk [20][50]  (h[t,s] = sum_d hk[s][d-1] * y[t-d,s])
  for (int idx = threadIdx.x; idx < SUBU * T_HISTK; idx += 256){
    int s = idx / T_HISTK, j = idx % T_HISTK;
    float delta = ldany(Dhist, s, bf);
    float acc = 0.f;
    for (int b = 0; b < HBAS; ++b){
      float tau = __expf(ldany(Tauhist, b, bf));
      float w   = ldany(Whist, s*HBAS + b, bf);
      float tt  = fmaxf((float)j - delta, 0.f) / tau;
      acc += w * tt * __expf(-tt);
    }
    ws[OFF_HK + s*T_HISTK + j] = acc;
  }
  // sparse M[s][s'] = C_den[s][s'] * W_sub[s']
  if (threadIdx.x < SUBU){
    int s = threadIdx.x, cnt = 0;
    for (int sp = 0; sp < SUBU; ++sp){
      float c = ldany(Cden, s*SUBU + sp, bf);
      if (c != 0.f && cnt < KMAX){
        ws[OFF_MW + s*KMAX + cnt]  = c * ldany(Wsub, sp, bf);
        wsi[OFF_MIDX + s*KMAX + cnt] = sp;
        ++cnt;
      }
    }
    for (int k = cnt; k < KMAX; ++k){
      ws[OFF_MW + s*KMAX + k] = 0.f; wsi[OFF_MIDX + s*KMAX + k] = 0;
    }
    ws[OFF_PAR + s] = ldany(Theta, s, bf);
  }
  if (threadIdx.x == 0){
    ws[OFF_PAR + SUBU]     = ldany(Wsub, 0, bf);
    ws[OFF_PAR + SUBU + 1] = ldany(Vo, 0, bf);
  }
}

// ---------------- skinny GEMM: in_T[s][t] = sum_e S[t][e]*C[s][e] ---------
template<int BF>
__device__ __forceinline__ void gemm_impl(const void* S, const void* C, int W,
                                          float* dst, int t0, int lane){
  float acc[4][SUBU];
  #pragma unroll
  for (int r = 0; r < 4; ++r)
    #pragma unroll
    for (int s = 0; s < SUBU; ++s) acc[r][s] = 0.f;
  for (int e = lane; e < W; e += 64){
    float s0 = ldany(S, (t0+0)*W + e, BF);
    float s1 = ldany(S, (t0+1)*W + e, BF);
    float s2 = ldany(S, (t0+2)*W + e, BF);
    float s3 = ldany(S, (t0+3)*W + e, BF);
    #pragma unroll
    for (int s = 0; s < SUBU; ++s){
      float c = ldany(C, s*W + e, BF);
      acc[0][s] = fmaf(s0, c, acc[0][s]);
      acc[1][s] = fmaf(s1, c, acc[1][s]);
      acc[2][s] = fmaf(s2, c, acc[2][s]);
      acc[3][s] = fmaf(s3, c, acc[3][s]);
    }
  }
  #pragma unroll
  for (int r = 0; r < 4; ++r){
    #pragma unroll
    for (int s = 0; s < SUBU; ++s){
      float v = acc[r][s];
      #pragma unroll
      for (int m = 32; m >= 1; m >>= 1) v += __shfl_xor(v, m, 64);
      if (lane == 0) dst[s*TPAD + t0 + r] = v;
    }
  }
}

__global__ __launch_bounds__(64) void k_gemm(const void* S, const void* C, int W,
                                             float* dst, const int* flagp){
  int t0 = blockIdx.x * 4, lane = threadIdx.x;
  if (*flagp) gemm_impl<1>(S, C, W, dst, t0, lane);
  else        gemm_impl<0>(S, C, W, dst, t0, lane);
}

// ---------------- causal conv: syn[t][s] = sum_k ke[s][k]*in_e[t-k][s]+... -
__global__ __launch_bounds__(256) void k_conv(float* ws){
  const int s  = blockIdx.y;
  const int t0 = blockIdx.x * 256;
  const float* ine = ws + OFF_INE + s*TPAD;
  const float* ini = ws + OFF_INI + s*TPAD;
  __shared__ float eL[455], iL[455], keL[T_SYNK], kiL[T_SYNK];
  for (int j = threadIdx.x; j < 455; j += 256){
    int t = t0 - 199 + j;
    bool ok = (t >= 0 && t < TPAD);
    eL[j] = ok ? ine[t] : 0.f;
    iL[j] = ok ? ini[t] : 0.f;
  }
  for (int j = threadIdx.x; j < T_SYNK; j += 256){
    keL[j] = ws[OFF_KE + s*T_SYNK + j];
    kiL[j] = ws[OFF_KI + s*T_SYNK + j];
  }
  __syncthreads();
  int t = t0 + threadIdx.x;
  if (t < TPAD){
    float a0 = 0.f, a1 = 0.f;
    #pragma unroll 4
    for (int k = 0; k < T_SYNK; ++k){
      a0 = fmaf(keL[k], eL[threadIdx.x + 199 - k], a0);
      a1 = fmaf(kiL[k], iL[threadIdx.x + 199 - k], a1);
    }
    ws[OFF_SYN + t*SUBU + s] = a0 + a1;
  }
}

// ---------------- sequential scan: one wave, lane s = subunit s -----------
__device__ __forceinline__ void itblock16(int tbase,
    float (&use)[16], float (&pre)[16], float (&yhv)[66],
    const float (&hk)[T_HISTK], const float (&mw)[KMAX], const int (&mad)[KMAX],
    float theta, float wsub0, float vo, const float* syng, int ss, int lane,
    void* outp, int bf){
  // prefetch next 16 steps' syn (consumed one block later; hides L2/L3 latency)
  #pragma unroll
  for (int u = 0; u < 16; ++u) pre[u] = syng[(tbase + 16 + u)*SUBU + ss];
  #pragma unroll
  for (int u = 0; u < 16; ++u){
    // history: h = sum_{j=0..49} hk[49-j] * yhv[u+j]   (yhv[u+49] = y[t-1])
    float h0 = 0.f, h1 = 0.f, h2 = 0.f, h3 = 0.f;
    #pragma unroll
    for (int j = 0; j < 48; j += 4){
      h0 = fmaf(hk[49 - j],     yhv[u + j],     h0);
      h1 = fmaf(hk[48 - j],     yhv[u + j + 1], h1);
      h2 = fmaf(hk[47 - j],     yhv[u + j + 2], h2);
      h3 = fmaf(hk[46 - j],     yhv[u + j + 3], h3);
    }
    h0 = fmaf(hk[1], yhv[u + 48], h0);
    h1 = fmaf(hk[0], yhv[u + 49], h1);
    // sparse cross-subunit coupling via bpermute of y[t-1]
    int yb = __float_as_int(yhv[u + 49]);
    float p0 = 0.f, p1 = 0.f;
    #pragma unroll
    for (int k = 0; k < KMAX; k += 2){
      p0 = fmaf(mw[k],   __int_as_float(__builtin_amdgcn_ds_bpermute(mad[k],   yb)), p0);
      p1 = fmaf(mw[k+1], __int_as_float(__builtin_amdgcn_ds_bpermute(mad[k+1], yb)), p1);
    }
    float x  = use[u] + theta + ((h0 + h1) + (h2 + h3)) + (p0 + p1);
    float ex = __expf(2.f * x);
    float y  = 1.f - __fdividef(2.f, ex + 1.f);
    yhv[u + 50] = y;
    int t = tbase + u;
    if (lane == 0 && t < T_DATA){
      float o = fmaf(y, wsub0, vo);
      if (bf) ((__hip_bfloat16*)outp)[t] = __float2bfloat16(o);
      else    ((float*)outp)[t] = o;
    }
  }
  #pragma unroll
  for (int j = 0; j < 50; ++j) yhv[j] = yhv[j + 16];
}

__global__ __launch_bounds__(64) void k_scan(float* ws, void* outp){
  const int lane = threadIdx.x;
  const int ss = lane < SUBU ? lane : SUBU - 1;
  const int* wsi = (const int*)ws;
  const int bf = wsi[OFF_FLAG];
  float hk[T_HISTK];
  #pragma unroll
  for (int j = 0; j < T_HISTK; ++j) hk[j] = ws[OFF_HK + ss*T_HISTK + j];
  float mw[KMAX]; int mad[KMAX];
  #pragma unroll
  for (int k = 0; k < KMAX; ++k){
    mw[k]  = ws[OFF_MW + ss*KMAX + k];
    mad[k] = wsi[OFF_MIDX + ss*KMAX + k] * 4;   // bpermute byte addr
  }
  const float theta = ws[OFF_PAR + ss];
  const float wsub0 = ws[OFF_PAR + SUBU];
  const float vo    = ws[OFF_PAR + SUBU + 1];
  float yhv[66];
  #pragma unroll
  for (int j = 0; j < 66; ++j) yhv[j] = 0.f;
  const float* syng = ws + OFF_SYN;
  float cur[16], nxt[16];
  #pragma unroll
  for (int u = 0; u < 16; ++u) cur[u] = syng[u*SUBU + ss];
  #pragma unroll 1
  for (int ib = 0; ib < 628; ++ib){               // 628*32 = 20096 steps
    itblock16(ib*32,      cur, nxt, yhv, hk, mw, mad, theta, wsub0, vo, syng, ss, lane, outp, bf);
    itblock16(ib*32 + 16, nxt, cur, yhv, hk, mw, mad, theta, wsub0, vo, syng, ss, lane, outp, bf);
  }
}

// --------------------------------------------------------------------------
extern "C" void kernel_launch(void* const* d_in, const int* in_sizes, int n_in,
                              void* d_out, int out_size, void* d_ws, size_t ws_size,
                              hipStream_t stream){
  const void* S_e   = d_in[0];
  const void* S_i   = d_in[1];
  const void* C_den = d_in[2];
  const void* C_e   = d_in[3];
  const void* C_i   = d_in[4];
  const void* W_syn = d_in[5];
  const void* Tau_s = d_in[6];
  const void* D_syn = d_in[7];
  const void* W_hst = d_in[8];
  const void* Tau_h = d_in[9];
  const void* D_hst = d_in[10];
  const void* W_sub = d_in[11];
  const void* V_o   = d_in[12];
  const void* Theta = d_in[13];
  float* ws = (float*)d_ws;
  int* flagp = (int*)(ws + OFF_FLAG);

  k_detect<<<1, 256, 0, stream>>>(S_e, flagp);
  k_prep<<<1, 256, 0, stream>>>(C_den, W_syn, Tau_s, D_syn, W_hst, Tau_h, D_hst,
                                W_sub, V_o, Theta, ws);
  k_gemm<<<5000, 64, 0, stream>>>(S_e, C_e, E_NO, ws + OFF_INE, flagp);
  k_gemm<<<5000, 64, 0, stream>>>(S_i, C_i, I_NO, ws + OFF_INI, flagp);
  dim3 cgrid(79, 20);
  k_conv<<<cgrid, 256, 0, stream>>>(ws);
  k_scan<<<1, 64, 0, stream>>>(ws, d_out);
}

// Round 2
// 2950.845 us; speedup vs baseline: 2.1014x; 2.1014x over previous
//
#include <hip/hip_runtime.h>
#include <hip/hip_bf16.h>
#include <stdint.h>

#define SUBU 20
#define E_NO 2000
#define I_NO 500
#define T_DATA 20000
#define T_SYNK 200
#define T_HISTK 50
#define SBAS 3
#define HBAS 3
#define TPAD 20096          // 1256 * 16
#define KSTORE 12           // storage slots for C_den nnz per row

// workspace float offsets
#define OFF_SYN  0          // [TPAD][20]  (c[t][s] = syn + theta)
#define OFF_INE  401920     // [20][TPAD]  (reused as Y[20000] by scan)
#define OFF_INI  803840     // [20][TPAD]
#define OFF_KE   1205760    // [20][200]
#define OFF_KI   1209760    // [20][200]
#define OFF_IIR  1213760    // [3][20][8] IIR consts
#define OFF_MW   1214760    // [20][KSTORE]
#define OFF_MIDX 1215000    // [20][KSTORE] ints
#define OFF_PAR  1215240    // theta[20], wsub0, vo, (unused), ksel(int)
#define OFF_FLAG 1215264    // int bf16 flag
#define OFF_Y    OFF_INE

__device__ __forceinline__ float bf2f(unsigned short u){
  unsigned v = ((unsigned)u) << 16; float f; __builtin_memcpy(&f, &v, 4); return f;
}
__device__ __forceinline__ float ldany(const void* p, int i, int bf){
  return bf ? bf2f(((const unsigned short*)p)[i]) : ((const float*)p)[i];
}

// ---------------- dtype detection: S_e is exactly {0,1} -------------------
__global__ __launch_bounds__(256) void k_detect(const void* s_e, int* flag){
  __shared__ int found;
  if (threadIdx.x == 0) found = 0;
  __syncthreads();
  const unsigned* w = (const unsigned*)s_e;
  int hit = 0;
  for (int i = threadIdx.x; i < 65536; i += 256){
    unsigned x = w[i];
    if (x == 0x00003F80u || x == 0x3F803F80u) hit = 1;   // bf16 1.0 patterns
  }
  if (hit) atomicOr(&found, 1);
  __syncthreads();
  if (threadIdx.x == 0) *flag = found;
}

// ---------------- precompute: syn kernels, IIR consts, sparse M, params ---
__global__ __launch_bounds__(256) void k_prep(
    const void* Cden, const void* Wsyn, const void* Tausyn, const void* Dsyn,
    const void* Whist, const void* Tauhist, const void* Dhist,
    const void* Wsub, const void* Vo, const void* Theta, float* ws){
  int* wsi = (int*)ws;
  const int bf = wsi[OFF_FLAG];
  __shared__ int mx;
  if (threadIdx.x == 0) mx = 0;
  __syncthreads();
  // synaptic kernels ke/ki [20][200]
  for (int idx = threadIdx.x; idx < SUBU * T_SYNK; idx += 256){
    int s = idx / T_SYNK, t = idx % T_SYNK;
    for (int c = 0; c < 2; ++c){
      float delta = __expf(ldany(Dsyn, s*2 + c, bf));
      float acc = 0.f;
      for (int b = 0; b < SBAS; ++b){
        float tau = __expf(ldany(Tausyn, b*2 + c, bf));
        float w   = ldany(Wsyn, (s*SBAS + b)*2 + c, bf);
        float tt  = fmaxf((float)t - delta, 0.f) / tau;
        acc += w * tt * __expf(-tt);
      }
      ws[(c == 0 ? OFF_KE : OFF_KI) + s*T_SYNK + t] = acc;
    }
  }
  // history windowed-IIR constants: h[t] = sum_b w_b * A_b[t],
  // A_b[t] = sum_{d=1}^{49} g_b(d) y[t-1-d], g_b(d)=((d-dl)/tau) e^{-(d-dl)/tau}
  if (threadIdx.x < SUBU * HBAS){
    int s = threadIdx.x / HBAS, b = threadIdx.x % HBAS;
    float tau = __expf(ldany(Tauhist, b, bf));
    float w   = ldany(Whist, s*HBAS + b, bf);
    float dl  = ldany(Dhist, s, bf);
    float rho = __expf(-1.f / tau);
    float e1  = __expf(-(1.f - dl) / tau);
    float g1  = ((1.f - dl) / tau) * e1;
    float e49 = __expf(-(49.f - dl) / tau);
    float g49 = ((49.f - dl) / tau) * e49;
    float kap = rho / tau;
    float* c = ws + OFF_IIR + (b*SUBU + s)*8;
    c[0] = rho;                       // A,E decay
    c[1] = w * kap;                   // E -> A coupling (scaled)
    c[2] = w * g1;                    // y_new coeff into A (scaled)
    c[3] = w * (rho*g49 + kap*e49);   // y_old coeff out of A (scaled)
    c[4] = e1;                        // y_new coeff into E
    c[5] = rho * e49;                 // y_old coeff out of E
  }
  // sparse M[s][s'] = C_den[s][s'] * W_sub[s']
  if (threadIdx.x < SUBU){
    int s = threadIdx.x, cnt = 0;
    for (int sp = 0; sp < SUBU; ++sp){
      float c = ldany(Cden, s*SUBU + sp, bf);
      if (c != 0.f && cnt < KSTORE){
        ws[OFF_MW + s*KSTORE + cnt]  = c * ldany(Wsub, sp, bf);
        wsi[OFF_MIDX + s*KSTORE + cnt] = sp;
        ++cnt;
      }
    }
    for (int k = cnt; k < KSTORE; ++k){
      ws[OFF_MW + s*KSTORE + k] = 0.f; wsi[OFF_MIDX + s*KSTORE + k] = 0;
    }
    atomicMax(&mx, cnt);
    ws[OFF_PAR + s] = ldany(Theta, s, bf);
  }
  __syncthreads();
  if (threadIdx.x == 0){
    ws[OFF_PAR + SUBU]     = ldany(Wsub, 0, bf);
    ws[OFF_PAR + SUBU + 1] = ldany(Vo, 0, bf);
    int k = (mx <= 6) ? 6 : (mx <= 8 ? 8 : 12);
    wsi[OFF_PAR + 23] = k;
  }
}

// ---------------- skinny GEMM: in_T[s][t] = sum_e S[t][e]*C[s][e] ---------
template<int BF>
__device__ __forceinline__ void gemm_impl(const void* S, const void* C, int W,
                                          float* dst, int t0, int lane){
  float acc[4][SUBU];
  #pragma unroll
  for (int r = 0; r < 4; ++r)
    #pragma unroll
    for (int s = 0; s < SUBU; ++s) acc[r][s] = 0.f;
  for (int e = lane; e < W; e += 64){
    float s0 = ldany(S, (t0+0)*W + e, BF);
    float s1 = ldany(S, (t0+1)*W + e, BF);
    float s2 = ldany(S, (t0+2)*W + e, BF);
    float s3 = ldany(S, (t0+3)*W + e, BF);
    #pragma unroll
    for (int s = 0; s < SUBU; ++s){
      float c = ldany(C, s*W + e, BF);
      acc[0][s] = fmaf(s0, c, acc[0][s]);
      acc[1][s] = fmaf(s1, c, acc[1][s]);
      acc[2][s] = fmaf(s2, c, acc[2][s]);
      acc[3][s] = fmaf(s3, c, acc[3][s]);
    }
  }
  #pragma unroll
  for (int r = 0; r < 4; ++r){
    #pragma unroll
    for (int s = 0; s < SUBU; ++s){
      float v = acc[r][s];
      #pragma unroll
      for (int m = 32; m >= 1; m >>= 1) v += __shfl_xor(v, m, 64);
      if (lane == 0) dst[s*TPAD + t0 + r] = v;
    }
  }
}

__global__ __launch_bounds__(64) void k_gemm(const void* S, const void* C, int W,
                                             float* dst, const int* flagp){
  int t0 = blockIdx.x * 4, lane = threadIdx.x;
  if (*flagp) gemm_impl<1>(S, C, W, dst, t0, lane);
  else        gemm_impl<0>(S, C, W, dst, t0, lane);
}

// ---------------- causal conv (+theta fold): c[t][s] ----------------------
__global__ __launch_bounds__(256) void k_conv(float* ws){
  const int s  = blockIdx.y;
  const int t0 = blockIdx.x * 256;
  const float* ine = ws + OFF_INE + s*TPAD;
  const float* ini = ws + OFF_INI + s*TPAD;
  __shared__ float eL[455], iL[455], keL[T_SYNK], kiL[T_SYNK];
  for (int j = threadIdx.x; j < 455; j += 256){
    int t = t0 - 199 + j;
    bool ok = (t >= 0 && t < TPAD);
    eL[j] = ok ? ine[t] : 0.f;
    iL[j] = ok ? ini[t] : 0.f;
  }
  for (int j = threadIdx.x; j < T_SYNK; j += 256){
    keL[j] = ws[OFF_KE + s*T_SYNK + j];
    kiL[j] = ws[OFF_KI + s*T_SYNK + j];
  }
  __syncthreads();
  int t = t0 + threadIdx.x;
  if (t < TPAD){
    float a0 = 0.f, a1 = 0.f;
    #pragma unroll 4
    for (int k = 0; k < T_SYNK; ++k){
      a0 = fmaf(keL[k], eL[threadIdx.x + 199 - k], a0);
      a1 = fmaf(kiL[k], iL[threadIdx.x + 199 - k], a1);
    }
    ws[OFF_SYN + t*SUBU + s] = a0 + a1 + ws[OFF_PAR + s];
  }
}

// ---------------- sequential scan: 1 wave, 3 lane-groups x 20 subunits ----
template<int KM>
__device__ __forceinline__ void itblock16(int tbase,
    float (&use)[16], float (&pre)[16], float (&yhv)[66],
    float &Aq, float &Eq, float &xpre,
    const float (&mw)[KM], const int (&mad)[KM], int gad0, int gad1,
    float c_rho, float c_kE, float c_yn, float c_yoA, float c_e1, float c_yoE,
    float wsub0, float vo, const float* syng, float* yout, int s, int lane){
  // prefetch next 16 steps' c (consumed one block later)
  #pragma unroll
  for (int u = 0; u < 16; ++u) pre[u] = syng[(tbase + 16 + u)*SUBU + s];
  #pragma unroll
  for (int u = 0; u < 16; ++u){
    float yprev = yhv[u + 49];                 // y[t-1]
    int yb = __float_as_int(yprev);
    float pb[KM];
    #pragma unroll
    for (int k = 0; k < KM; ++k)
      pb[k] = __int_as_float(__builtin_amdgcn_ds_bpermute(mad[k], yb));
    // windowed-IIR history update for h[t+1] (off critical path)
    float yold = yhv[u];                       // y[t-50]
    float An = fmaf(c_kE, Eq, c_rho * Aq);
    An = fmaf(c_yn, yprev, An);
    An = fmaf(-c_yoA, yold, An);
    Eq = fmaf(c_e1, yprev, c_rho * Eq);
    Eq = fmaf(-c_yoE, yold, Eq);
    Aq = An;
    float b0 = __int_as_float(__builtin_amdgcn_ds_bpermute(gad0, __float_as_int(Aq)));
    float b1 = __int_as_float(__builtin_amdgcn_ds_bpermute(gad1, __float_as_int(Aq)));
    // prop = sum_k mw[k] * y[t-1][idx[k]]  (two chains + combine)
    float p0 = mw[0] * pb[0];
    float p1 = mw[1] * pb[1];
    #pragma unroll
    for (int k = 2; k + 1 < KM; k += 2){
      p0 = fmaf(mw[k],   pb[k],   p0);
      p1 = fmaf(mw[k+1], pb[k+1], p1);
    }
    float x = xpre + (p0 + p1);
    // tanh(x) = 1 - 2/(exp2(2*log2e*x)+1)
    float ex = __builtin_amdgcn_exp2f(2.885390082f * x);
    float y  = fmaf(-2.f, __builtin_amdgcn_rcpf(ex + 1.f), 1.f);
    yhv[u + 50] = y;
    // h[t+1] gather across bases + next-step partial x
    float hnext = (Aq + b0) + b1;
    float cn = (u < 15) ? use[u+1] : pre[0];
    xpre = cn + hnext;
    int t = tbase + u;
    if (lane == 0 && t < T_DATA) yout[t] = fmaf(y, wsub0, vo);
  }
  #pragma unroll
  for (int j = 0; j < 50; ++j) yhv[j] = yhv[j + 16];
}

template<int KM>
__global__ __launch_bounds__(64) void k_scan(float* ws){
  const int* wsi = (const int*)ws;
  if (wsi[OFF_PAR + 23] != KM) return;        // KMAX variant select
  const int lane = threadIdx.x;
  int g = lane / 20, s = lane % 20;
  if (lane >= 60){ g = 2; s = lane - 44; }    // lanes 60-63 mirror g=2,s=16..19
  const float* cc = ws + OFF_IIR + (g*SUBU + s)*8;
  const float c_rho = cc[0], c_kE = cc[1], c_yn = cc[2],
              c_yoA = cc[3], c_e1 = cc[4], c_yoE = cc[5];
  float mw[KM]; int mad[KM];
  #pragma unroll
  for (int k = 0; k < KM; ++k){
    mw[k]  = ws[OFF_MW + s*KSTORE + k];
    mad[k] = (g*SUBU + wsi[OFF_MIDX + s*KSTORE + k]) * 4;
  }
  const int gad0 = (((g + 1) % 3)*SUBU + s) * 4;
  const int gad1 = (((g + 2) % 3)*SUBU + s) * 4;
  const float wsub0 = ws[OFF_PAR + SUBU];
  const float vo    = ws[OFF_PAR + SUBU + 1];
  float* yout = ws + OFF_Y;
  const float* syng = ws + OFF_SYN;
  float yhv[66];
  #pragma unroll
  for (int j = 0; j < 66; ++j) yhv[j] = 0.f;
  float Aq = 0.f, Eq = 0.f;
  float cur[16], nxt[16];
  #pragma unroll
  for (int u = 0; u < 16; ++u) cur[u] = syng[u*SUBU + s];
  float xpre = cur[0];                         // h[0]=0
  #pragma unroll 1
  for (int ib = 0; ib < 628; ++ib){            // 628*32 = 20096 steps
    itblock16<KM>(ib*32,      cur, nxt, yhv, Aq, Eq, xpre, mw, mad, gad0, gad1,
                  c_rho, c_kE, c_yn, c_yoA, c_e1, c_yoE, wsub0, vo, syng, yout, s, lane);
    itblock16<KM>(ib*32 + 16, nxt, cur, yhv, Aq, Eq, xpre, mw, mad, gad0, gad1,
                  c_rho, c_kE, c_yn, c_yoA, c_e1, c_yoE, wsub0, vo, syng, yout, s, lane);
  }
}

// ---------------- epilogue: f32 Y -> output dtype --------------------------
__global__ __launch_bounds__(256) void k_out(const float* ws, void* outp){
  const int* wsi = (const int*)ws;
  const int bf = wsi[OFF_FLAG];
  int i = blockIdx.x * 256 + threadIdx.x;
  if (i < T_DATA){
    float v = ws[OFF_Y + i];
    if (bf) ((__hip_bfloat16*)outp)[i] = __float2bfloat16(v);
    else    ((float*)outp)[i] = v;
  }
}

// --------------------------------------------------------------------------
extern "C" void kernel_launch(void* const* d_in, const int* in_sizes, int n_in,
                              void* d_out, int out_size, void* d_ws, size_t ws_size,
                              hipStream_t stream){
  const void* S_e   = d_in[0];
  const void* S_i   = d_in[1];
  const void* C_den = d_in[2];
  const void* C_e   = d_in[3];
  const void* C_i   = d_in[4];
  const void* W_syn = d_in[5];
  const void* Tau_s = d_in[6];
  const void* D_syn = d_in[7];
  const void* W_hst = d_in[8];
  const void* Tau_h = d_in[9];
  const void* D_hst = d_in[10];
  const void* W_sub = d_in[11];
  const void* V_o   = d_in[12];
  const void* Theta = d_in[13];
  float* ws = (float*)d_ws;
  int* flagp = (int*)(ws + OFF_FLAG);

  k_detect<<<1, 256, 0, stream>>>(S_e, flagp);
  k_prep<<<1, 256, 0, stream>>>(C_den, W_syn, Tau_s, D_syn, W_hst, Tau_h, D_hst,
                                W_sub, V_o, Theta, ws);
  k_gemm<<<5000, 64, 0, stream>>>(S_e, C_e, E_NO, ws + OFF_INE, flagp);
  k_gemm<<<5000, 64, 0, stream>>>(S_i, C_i, I_NO, ws + OFF_INI, flagp);
  dim3 cgrid(79, 20);
  k_conv<<<cgrid, 256, 0, stream>>>(ws);
  k_scan<6><<<1, 64, 0, stream>>>(ws);
  k_scan<8><<<1, 64, 0, stream>>>(ws);
  k_scan<12><<<1, 64, 0, stream>>>(ws);
  k_out<<<79, 256, 0, stream>>>(ws, d_out);
}